// Round 2
// baseline (669.734 us; speedup 1.0000x reference)
//
#include <hip/hip_runtime.h>
#include <hip/hip_bf16.h>

#define N_NODES 10000
#define N_EDGES 320000
#define N_REL   460
#define N_BASES 30
#define DIM     200
#define KZ      6016   // 30*200=6000 padded to multiple of 32
#define KT      6240   // KZ + 224 (self-term columns appended)
#define NPAD    224    // 200 padded col dim for B
#define NF      13     // 13 col fragments of 16 = 208 >= 200
#define NSTEPS  195    // KT/32

using short8  = __attribute__((ext_vector_type(8))) short;
using floatx4 = __attribute__((ext_vector_type(4))) float;

__device__ __forceinline__ unsigned short f2bf(float f) {
    union { float f; unsigned u; } v; v.f = f;
    unsigned u = v.u;
    return (unsigned short)((u + 0x7fffu + ((u >> 16) & 1u)) >> 16);
}

// ---------------- sort-by-target (counting sort) ----------------

__global__ void zero_deg_kernel(int* deg) {
    int i = blockIdx.x * blockDim.x + threadIdx.x;
    if (i < N_NODES) deg[i] = 0;
}

__global__ void hist_kernel(const int* tgt, int* deg) {
    int e = blockIdx.x * blockDim.x + threadIdx.x;
    if (e < N_EDGES) atomicAdd(&deg[tgt[e]], 1);
}

__global__ __launch_bounds__(1024) void scan_kernel(const int* deg, int* starts,
                                                    int* cursor, float* dinv) {
    __shared__ int part[1024];
    int tid = threadIdx.x;
    const int PER = (N_NODES + 1023) / 1024;  // 10
    int base = tid * PER;
    int s = 0;
    for (int i = 0; i < PER; ++i) { int idx = base + i; if (idx < N_NODES) s += deg[idx]; }
    part[tid] = s; __syncthreads();
    for (int off = 1; off < 1024; off <<= 1) {
        int v = (tid >= off) ? part[tid - off] : 0;
        __syncthreads();
        part[tid] += v;
        __syncthreads();
    }
    int run = (tid > 0) ? part[tid - 1] : 0;
    for (int i = 0; i < PER; ++i) {
        int idx = base + i;
        if (idx < N_NODES) {
            int d = deg[idx];
            starts[idx] = run; cursor[idx] = run;
            dinv[idx] = 1.0f / (float)(d > 0 ? d : 1);
            run += d;
        }
    }
    if (tid == 1023) starts[N_NODES] = part[1023];
}

__global__ void scatter_kernel(const int* src, const int* tgt, const int* etype,
                               int* cursor, int* ssrc, int* stype) {
    int e = blockIdx.x * blockDim.x + threadIdx.x;
    if (e < N_EDGES) {
        int t = tgt[e];
        int pos = atomicAdd(&cursor[t], 1);
        ssrc[pos]  = src[e];
        stype[pos] = etype[e];
    }
}

// ---------------- bf16 operand prep ----------------
// B_ext[c][k] : k<KZ -> weight[b][kk][c] (k=b*200+kk); k in [KZ,KT) -> selfw[j][c]

__global__ void fill_bt_kernel(const float* weight, unsigned short* BW) {
    int idx = blockIdx.x * blockDim.x + threadIdx.x;
    if (idx >= NPAD * KZ) return;
    int n = idx / KZ, k = idx - n * KZ;
    float v = 0.f;
    if (n < DIM && k < N_BASES * DIM) {
        int b = k / DIM, kk = k - b * DIM;
        v = weight[(b * DIM + kk) * DIM + n];
    }
    BW[(size_t)n * KT + k] = f2bf(v);
}

__global__ void fill_wst_kernel(const float* sw, unsigned short* BW) {
    int idx = blockIdx.x * blockDim.x + threadIdx.x;
    if (idx >= NPAD * NPAD) return;
    int c = idx / NPAD, j = idx - c * NPAD;
    float v = (c < DIM && j < DIM) ? sw[j * DIM + c] : 0.f;
    BW[(size_t)c * KT + KZ + j] = f2bf(v);
}

// A_ext[n][KZ + j] = max(deg,1) * x[n][j]  (dinv applied in epilogue undoes it)
__global__ void fill_xb_kernel(const float* x, const int* deg, unsigned short* ZX) {
    int idx = blockIdx.x * blockDim.x + threadIdx.x;
    if (idx >= N_NODES * NPAD) return;
    int n = idx / NPAD, j = idx - n * NPAD;
    float v = 0.f;
    if (j < DIM) {
        int d = deg[n]; if (d < 1) d = 1;
        v = (float)d * x[(size_t)n * DIM + j];
    }
    ZX[(size_t)n * KT + KZ + j] = f2bf(v);
}

// ---------------- per-target-node aggregation into Z ----------------
// ZX[n][b*200+d] = sum over incoming edges of coeff[type,b] * x[src,d].
// 8 edges staged per barrier pair. Thread (tb=tid&7, td=tid>>3) owns
// bases tb*4..+3 and cols td*7..+6.

__global__ __launch_bounds__(256) void agg_kernel(const float* x, const float* coeff,
                                                  const int* starts, const int* ssrc,
                                                  const int* stype, unsigned short* ZX) {
    __shared__ float xs[8][NPAD];   // 7168 B
    __shared__ float cs[8][32];     // 1024 B
    __shared__ __align__(16) unsigned short zs[KZ];
    int n = blockIdx.x;
    int tid = threadIdx.x;
    int tb = tid & 7;
    int td = tid >> 3;
    float acc[4][7];
#pragma unroll
    for (int i = 0; i < 4; ++i)
#pragma unroll
        for (int j = 0; j < 7; ++j) acc[i][j] = 0.f;

    int e0 = starts[n], e1 = starts[n + 1];
    for (int eb = e0; eb < e1; eb += 8) {
        // stage 8 x-rows: 8*224 = 1792 = 7*256
#pragma unroll
        for (int i = 0; i < 7; ++i) {
            int idx = tid + i * 256;
            int row = idx / NPAD;
            int col = idx - row * NPAD;
            int e = eb + row;
            float v = 0.f;
            if (e < e1 && col < DIM) v = x[(size_t)ssrc[e] * DIM + col];
            xs[row][col] = v;
        }
        {
            int ee = tid >> 5, j = tid & 31;
            int e = eb + ee;
            float v = 0.f;
            if (e < e1 && j < N_BASES) v = coeff[stype[e] * N_BASES + j];
            cs[ee][j] = v;
        }
        __syncthreads();
#pragma unroll
        for (int ee = 0; ee < 8; ++ee) {
            float c[4], xx[7];
#pragma unroll
            for (int i = 0; i < 4; ++i) c[i] = cs[ee][tb * 4 + i];
#pragma unroll
            for (int j = 0; j < 7; ++j) xx[j] = xs[ee][td * 7 + j];
#pragma unroll
            for (int i = 0; i < 4; ++i)
#pragma unroll
                for (int j = 0; j < 7; ++j) acc[i][j] += c[i] * xx[j];
        }
        __syncthreads();
    }
    if (tid < KZ - N_BASES * DIM) zs[N_BASES * DIM + tid] = 0;  // pad 6000..6015
#pragma unroll
    for (int i = 0; i < 4; ++i) {
        int b = tb * 4 + i;
#pragma unroll
        for (int j = 0; j < 7; ++j) {
            int d = td * 7 + j;
            if (b < N_BASES && d < DIM) zs[b * DIM + d] = f2bf(acc[i][j]);
        }
    }
    __syncthreads();
    const uint4* zv  = (const uint4*)zs;
    uint4*       dst = (uint4*)(ZX + (size_t)n * KT);
    for (int idx = tid; idx < (KZ * 2) / 16; idx += 256) dst[idx] = zv[idx];
}

// ---------------- GEMM: out = dinv * (A_ext @ B_ext^T) + bias ----------------
// Block = 32 rows x 208 cols; 4 waves split K (195 ksteps -> 49/49/49/48),
// LDS reduction across waves, epilogue applies dinv & bias.

__global__ __launch_bounds__(256) void gemm_kernel(const unsigned short* A,
                                                   const unsigned short* B,
                                                   const float* dinv, const float* bias,
                                                   float* out) {
    __shared__ float red[32 * 208];  // 26624 B
    int tid = threadIdx.x;
    int lane = tid & 63, wave = tid >> 6;
    int row0 = blockIdx.x * 32;
    int ln = lane & 15, q = lane >> 4;
    int r0 = min(row0 + ln, N_NODES - 1);
    int r1 = min(row0 + 16 + ln, N_NODES - 1);
    const unsigned short* pa0 = A + (size_t)r0 * KT + q * 8;
    const unsigned short* pa1 = A + (size_t)r1 * KT + q * 8;
    const unsigned short* pb  = B + (size_t)ln * KT + q * 8;

    int ks = wave * 49;
    int ke = min(ks + 49, NSTEPS);

    floatx4 acc0[NF], acc1[NF];
#pragma unroll
    for (int f = 0; f < NF; ++f) {
        acc0[f] = (floatx4){0.f, 0.f, 0.f, 0.f};
        acc1[f] = acc0[f];
    }

    for (int kk = ks; kk < ke; ++kk) {
        int k = kk * 32;
        short8 a0 = *(const short8*)(pa0 + k);
        short8 a1 = *(const short8*)(pa1 + k);
#pragma unroll
        for (int f = 0; f < NF; ++f) {
            short8 b = *(const short8*)(pb + (size_t)f * 16 * KT + k);
            acc0[f] = __builtin_amdgcn_mfma_f32_16x16x32_bf16(a0, b, acc0[f], 0, 0, 0);
            acc1[f] = __builtin_amdgcn_mfma_f32_16x16x32_bf16(a1, b, acc1[f], 0, 0, 0);
        }
    }

    // cross-wave reduction in LDS (serial over waves)
    for (int w = 0; w < 4; ++w) {
        if (wave == w) {
#pragma unroll
            for (int f = 0; f < NF; ++f)
#pragma unroll
                for (int i = 0; i < 4; ++i) {
                    int c = f * 16 + ln;
                    int ra = (q * 4 + i) * 208 + c;
                    int rb = (16 + q * 4 + i) * 208 + c;
                    if (w == 0) { red[ra] = acc0[f][i]; red[rb] = acc1[f][i]; }
                    else        { red[ra] += acc0[f][i]; red[rb] += acc1[f][i]; }
                }
        }
        __syncthreads();
    }

    for (int idx = tid; idx < 32 * 208; idx += 256) {
        int r = idx / 208, c = idx - r * 208;
        int row = row0 + r;
        if (row < N_NODES && c < DIM)
            out[(size_t)row * DIM + c] = red[idx] * dinv[row] + bias[c];
    }
}

// ---------------- launch ----------------

extern "C" void kernel_launch(void* const* d_in, const int* in_sizes, int n_in,
                              void* d_out, int out_size, void* d_ws, size_t ws_size,
                              hipStream_t stream) {
    const float* x      = (const float*)d_in[0];
    const float* weight = (const float*)d_in[1];
    const float* coeff  = (const float*)d_in[2];
    const float* selfw  = (const float*)d_in[3];
    const float* bias   = (const float*)d_in[4];
    const int*   eidx   = (const int*)d_in[5];
    const int*   etype  = (const int*)d_in[6];
    const int* src = eidx;
    const int* tgt = eidx + N_EDGES;
    float* out = (float*)d_out;

    char* ws = (char*)d_ws;
    size_t off = 0;
    auto carve = [&](size_t bytes) {
        char* p = ws + off;
        off += (bytes + 255) & ~(size_t)255;
        return p;
    };
    unsigned short* ZX  = (unsigned short*)carve((size_t)N_NODES * KT * 2);
    unsigned short* BW  = (unsigned short*)carve((size_t)NPAD * KT * 2);
    int*   deg    = (int*)carve((size_t)N_NODES * 4);
    int*   starts = (int*)carve((size_t)(N_NODES + 1) * 4);
    int*   cursor = (int*)carve((size_t)N_NODES * 4);
    float* dinv   = (float*)carve((size_t)N_NODES * 4);
    int*   ssrc   = (int*)carve((size_t)N_EDGES * 4);
    int*   stype  = (int*)carve((size_t)N_EDGES * 4);

    zero_deg_kernel<<<(N_NODES + 255) / 256, 256, 0, stream>>>(deg);
    hist_kernel<<<(N_EDGES + 255) / 256, 256, 0, stream>>>(tgt, deg);
    scan_kernel<<<1, 1024, 0, stream>>>(deg, starts, cursor, dinv);
    scatter_kernel<<<(N_EDGES + 255) / 256, 256, 0, stream>>>(src, tgt, etype, cursor, ssrc, stype);

    fill_bt_kernel<<<(NPAD * KZ + 255) / 256, 256, 0, stream>>>(weight, BW);
    fill_wst_kernel<<<(NPAD * NPAD + 255) / 256, 256, 0, stream>>>(selfw, BW);
    fill_xb_kernel<<<(N_NODES * NPAD + 255) / 256, 256, 0, stream>>>(x, deg, ZX);

    agg_kernel<<<N_NODES, 256, 0, stream>>>(x, coeff, starts, ssrc, stype, ZX);

    gemm_kernel<<<(N_NODES + 31) / 32, 256, 0, stream>>>(ZX, BW, dinv, bias, out);
}

// Round 3
// 401.992 us; speedup vs baseline: 1.6660x; 1.6660x over previous
//
#include <hip/hip_runtime.h>
#include <hip/hip_bf16.h>

#define N_NODES 10000
#define N_EDGES 320000
#define N_REL   460
#define N_BASES 30
#define DIM     200
#define KZ      6016   // 30*200=6000 padded to multiple of 32
#define KT      6240   // KZ + 224 (self-term columns appended)
#define NPAD    224    // 200 padded col dim for B
#define NF      13     // 13 col fragments of 16 = 208 >= 200
#define NSTEPS  195    // KT/32

using short8  = __attribute__((ext_vector_type(8))) short;
using floatx4 = __attribute__((ext_vector_type(4))) float;

__device__ __forceinline__ unsigned short f2bf(float f) {
    union { float f; unsigned u; } v; v.f = f;
    unsigned u = v.u;
    return (unsigned short)((u + 0x7fffu + ((u >> 16) & 1u)) >> 16);
}

__device__ __forceinline__ float bits2f(unsigned u) {
    union { unsigned u; float f; } v; v.u = u;
    return v.f;
}

// ---------------- sort-by-target (counting sort) ----------------

__global__ void zero_deg_kernel(int* deg) {
    int i = blockIdx.x * blockDim.x + threadIdx.x;
    if (i < N_NODES) deg[i] = 0;
}

__global__ void hist_kernel(const int* tgt, int* deg) {
    int e = blockIdx.x * blockDim.x + threadIdx.x;
    if (e < N_EDGES) atomicAdd(&deg[tgt[e]], 1);
}

__global__ __launch_bounds__(1024) void scan_kernel(const int* deg, int* starts,
                                                    int* cursor, float* dinv) {
    __shared__ int part[1024];
    int tid = threadIdx.x;
    const int PER = (N_NODES + 1023) / 1024;  // 10
    int base = tid * PER;
    int s = 0;
    for (int i = 0; i < PER; ++i) { int idx = base + i; if (idx < N_NODES) s += deg[idx]; }
    part[tid] = s; __syncthreads();
    for (int off = 1; off < 1024; off <<= 1) {
        int v = (tid >= off) ? part[tid - off] : 0;
        __syncthreads();
        part[tid] += v;
        __syncthreads();
    }
    int run = (tid > 0) ? part[tid - 1] : 0;
    for (int i = 0; i < PER; ++i) {
        int idx = base + i;
        if (idx < N_NODES) {
            int d = deg[idx];
            starts[idx] = run; cursor[idx] = run;
            dinv[idx] = 1.0f / (float)(d > 0 ? d : 1);
            run += d;
        }
    }
    if (tid == 1023) starts[N_NODES] = part[1023];
}

__global__ void scatter_kernel(const int* src, const int* tgt, const int* etype,
                               int* cursor, int* ssrc, int* stype) {
    int e = blockIdx.x * blockDim.x + threadIdx.x;
    if (e < N_EDGES) {
        int t = tgt[e];
        int pos = atomicAdd(&cursor[t], 1);
        ssrc[pos]  = src[e];
        stype[pos] = etype[e];
    }
}

// ---------------- bf16 operand prep ----------------
// B_ext[c][k] : k<KZ -> weight[b][kk][c] (k=b*200+kk); k in [KZ,KT) -> selfw[j][c]

__global__ void fill_bt_kernel(const float* weight, unsigned short* BW) {
    int idx = blockIdx.x * blockDim.x + threadIdx.x;
    if (idx >= NPAD * KZ) return;
    int n = idx / KZ, k = idx - n * KZ;
    float v = 0.f;
    if (n < DIM && k < N_BASES * DIM) {
        int b = k / DIM, kk = k - b * DIM;
        v = weight[(b * DIM + kk) * DIM + n];
    }
    BW[(size_t)n * KT + k] = f2bf(v);
}

__global__ void fill_wst_kernel(const float* sw, unsigned short* BW) {
    int idx = blockIdx.x * blockDim.x + threadIdx.x;
    if (idx >= NPAD * NPAD) return;
    int c = idx / NPAD, j = idx - c * NPAD;
    float v = (c < DIM && j < DIM) ? sw[j * DIM + c] : 0.f;
    BW[(size_t)c * KT + KZ + j] = f2bf(v);
}

// A_ext[n][KZ + j] = max(deg,1) * x[n][j]  (dinv applied in epilogue undoes it)
__global__ void fill_xb_kernel(const float* x, const int* deg, unsigned short* ZX) {
    int idx = blockIdx.x * blockDim.x + threadIdx.x;
    if (idx >= N_NODES * NPAD) return;
    int n = idx / NPAD, j = idx - n * NPAD;
    float v = 0.f;
    if (j < DIM) {
        int d = deg[n]; if (d < 1) d = 1;
        v = (float)d * x[(size_t)n * DIM + j];
    }
    ZX[(size_t)n * KT + KZ + j] = f2bf(v);
}

// ---------------- per-target-node aggregation into Z ----------------
// Wave-per-node, barrier-free. Lane l (<50) owns cols 4l..4l+3; acc[30][4] in
// VGPRs. Coeff table staged once per block into LDS as bf16 (broadcast reads).

__global__ __launch_bounds__(256) void agg_kernel(const float* __restrict__ x,
                                                  const float* __restrict__ coeff,
                                                  const int* __restrict__ starts,
                                                  const int* __restrict__ ssrc,
                                                  const int* __restrict__ stype,
                                                  unsigned short* __restrict__ ZX) {
    __shared__ unsigned short c_lds[N_REL * N_BASES];  // 27600 B
    int tid = threadIdx.x;
    for (int i = tid; i < N_REL * N_BASES; i += 256)
        c_lds[i] = f2bf(coeff[i]);
    __syncthreads();

    int wave = tid >> 6;
    int lane = tid & 63;
    int n = blockIdx.x * 4 + wave;            // 2500*4 == 10000 exactly
    int cl = min(lane, 49);                   // clamp: lanes 50..63 duplicate

    float acc[N_BASES][4];
#pragma unroll
    for (int b = 0; b < N_BASES; ++b)
#pragma unroll
        for (int j = 0; j < 4; ++j) acc[b][j] = 0.f;

    int e0 = starts[n], e1 = starts[n + 1];
    const float4* x4 = (const float4*)x;      // 50 float4 per row

    float4 xvn = {0.f, 0.f, 0.f, 0.f};
    int tn = 0;
    if (e0 < e1) {
        int s0 = ssrc[e0];
        tn = stype[e0];
        xvn = x4[(size_t)s0 * 50 + cl];
    }

    for (int e = e0; e < e1; ++e) {
        float4 xv = xvn;
        int t = tn;
        const unsigned int* cw = (const unsigned int*)(c_lds + t * N_BASES);
        unsigned int w[N_BASES / 2];
#pragma unroll
        for (int i = 0; i < N_BASES / 2; ++i) w[i] = cw[i];  // broadcast ds_read

        if (e + 1 < e1) {                    // prefetch next edge
            int s1 = ssrc[e + 1];
            tn = stype[e + 1];
            xvn = x4[(size_t)s1 * 50 + cl];
        }

#pragma unroll
        for (int i = 0; i < N_BASES / 2; ++i) {
            float clo = bits2f(w[i] << 16);
            float chi = bits2f(w[i] & 0xffff0000u);
            acc[2 * i][0] += clo * xv.x; acc[2 * i][1] += clo * xv.y;
            acc[2 * i][2] += clo * xv.z; acc[2 * i][3] += clo * xv.w;
            acc[2 * i + 1][0] += chi * xv.x; acc[2 * i + 1][1] += chi * xv.y;
            acc[2 * i + 1][2] += chi * xv.z; acc[2 * i + 1][3] += chi * xv.w;
        }
    }

    if (lane < 50) {
        unsigned short* zr = ZX + (size_t)n * KT;
#pragma unroll
        for (int b = 0; b < N_BASES; ++b) {
            unsigned p0 = (unsigned)f2bf(acc[b][0]) | ((unsigned)f2bf(acc[b][1]) << 16);
            unsigned p1 = (unsigned)f2bf(acc[b][2]) | ((unsigned)f2bf(acc[b][3]) << 16);
            uint2 v; v.x = p0; v.y = p1;
            *(uint2*)(zr + b * DIM + lane * 4) = v;
        }
    }
}

// ---------------- GEMM: out = dinv * (A_ext @ B_ext^T) + bias ----------------
// Block = 32 rows x 208 cols; 4 waves split K (195 ksteps -> 49/49/49/48),
// LDS reduction across waves, epilogue applies dinv & bias.

__global__ __launch_bounds__(256) void gemm_kernel(const unsigned short* A,
                                                   const unsigned short* B,
                                                   const float* dinv, const float* bias,
                                                   float* out) {
    __shared__ float red[32 * 208];  // 26624 B
    int tid = threadIdx.x;
    int lane = tid & 63, wave = tid >> 6;
    int row0 = blockIdx.x * 32;
    int ln = lane & 15, q = lane >> 4;
    int r0 = min(row0 + ln, N_NODES - 1);
    int r1 = min(row0 + 16 + ln, N_NODES - 1);
    const unsigned short* pa0 = A + (size_t)r0 * KT + q * 8;
    const unsigned short* pa1 = A + (size_t)r1 * KT + q * 8;
    const unsigned short* pb  = B + (size_t)ln * KT + q * 8;

    int ks = wave * 49;
    int ke = min(ks + 49, NSTEPS);

    floatx4 acc0[NF], acc1[NF];
#pragma unroll
    for (int f = 0; f < NF; ++f) {
        acc0[f] = (floatx4){0.f, 0.f, 0.f, 0.f};
        acc1[f] = acc0[f];
    }

    for (int kk = ks; kk < ke; ++kk) {
        int k = kk * 32;
        short8 a0 = *(const short8*)(pa0 + k);
        short8 a1 = *(const short8*)(pa1 + k);
#pragma unroll
        for (int f = 0; f < NF; ++f) {
            short8 b = *(const short8*)(pb + (size_t)f * 16 * KT + k);
            acc0[f] = __builtin_amdgcn_mfma_f32_16x16x32_bf16(a0, b, acc0[f], 0, 0, 0);
            acc1[f] = __builtin_amdgcn_mfma_f32_16x16x32_bf16(a1, b, acc1[f], 0, 0, 0);
        }
    }

    // cross-wave reduction in LDS (serial over waves)
    for (int w = 0; w < 4; ++w) {
        if (wave == w) {
#pragma unroll
            for (int f = 0; f < NF; ++f)
#pragma unroll
                for (int i = 0; i < 4; ++i) {
                    int c = f * 16 + ln;
                    int ra = (q * 4 + i) * 208 + c;
                    int rb = (16 + q * 4 + i) * 208 + c;
                    if (w == 0) { red[ra] = acc0[f][i]; red[rb] = acc1[f][i]; }
                    else        { red[ra] += acc0[f][i]; red[rb] += acc1[f][i]; }
                }
        }
        __syncthreads();
    }

    for (int idx = tid; idx < 32 * 208; idx += 256) {
        int r = idx / 208, c = idx - r * 208;
        int row = row0 + r;
        if (row < N_NODES && c < DIM)
            out[(size_t)row * DIM + c] = red[idx] * dinv[row] + bias[c];
    }
}

// ---------------- launch ----------------

extern "C" void kernel_launch(void* const* d_in, const int* in_sizes, int n_in,
                              void* d_out, int out_size, void* d_ws, size_t ws_size,
                              hipStream_t stream) {
    const float* x      = (const float*)d_in[0];
    const float* weight = (const float*)d_in[1];
    const float* coeff  = (const float*)d_in[2];
    const float* selfw  = (const float*)d_in[3];
    const float* bias   = (const float*)d_in[4];
    const int*   eidx   = (const int*)d_in[5];
    const int*   etype  = (const int*)d_in[6];
    const int* src = eidx;
    const int* tgt = eidx + N_EDGES;
    float* out = (float*)d_out;

    char* ws = (char*)d_ws;
    size_t off = 0;
    auto carve = [&](size_t bytes) {
        char* p = ws + off;
        off += (bytes + 255) & ~(size_t)255;
        return p;
    };
    unsigned short* ZX  = (unsigned short*)carve((size_t)N_NODES * KT * 2);
    unsigned short* BW  = (unsigned short*)carve((size_t)NPAD * KT * 2);
    int*   deg    = (int*)carve((size_t)N_NODES * 4);
    int*   starts = (int*)carve((size_t)(N_NODES + 1) * 4);
    int*   cursor = (int*)carve((size_t)N_NODES * 4);
    float* dinv   = (float*)carve((size_t)N_NODES * 4);
    int*   ssrc   = (int*)carve((size_t)N_EDGES * 4);
    int*   stype  = (int*)carve((size_t)N_EDGES * 4);

    zero_deg_kernel<<<(N_NODES + 255) / 256, 256, 0, stream>>>(deg);
    hist_kernel<<<(N_EDGES + 255) / 256, 256, 0, stream>>>(tgt, deg);
    scan_kernel<<<1, 1024, 0, stream>>>(deg, starts, cursor, dinv);
    scatter_kernel<<<(N_EDGES + 255) / 256, 256, 0, stream>>>(src, tgt, etype, cursor, ssrc, stype);

    fill_bt_kernel<<<(NPAD * KZ + 255) / 256, 256, 0, stream>>>(weight, BW);
    fill_wst_kernel<<<(NPAD * NPAD + 255) / 256, 256, 0, stream>>>(selfw, BW);
    fill_xb_kernel<<<(N_NODES * NPAD + 255) / 256, 256, 0, stream>>>(x, deg, ZX);

    agg_kernel<<<N_NODES / 4, 256, 0, stream>>>(x, coeff, starts, ssrc, stype, ZX);

    gemm_kernel<<<(N_NODES + 31) / 32, 256, 0, stream>>>(ZX, BW, dinv, bias, out);
}

// Round 4
// 363.714 us; speedup vs baseline: 1.8414x; 1.1052x over previous
//
#include <hip/hip_runtime.h>
#include <hip/hip_bf16.h>

#define N_NODES 10000
#define N_EDGES 320000
#define N_REL   460
#define N_BASES 30
#define DIM     200
#define KZ      6016   // 30*200=6000 padded to multiple of 32
#define KT      6240   // KZ + 224 (self-term columns appended)
#define NPAD    224    // 224 rows allocated for B (col dim padded)
#define NSTEPS  195    // KT/32
#define NTILES  313    // ceil(10000/32)
#define KSPLIT  4
#define PROWS   10016  // 313*32

using short8  = __attribute__((ext_vector_type(8))) short;
using floatx4 = __attribute__((ext_vector_type(4))) float;

__device__ __forceinline__ unsigned short f2bf(float f) {
    union { float f; unsigned u; } v; v.f = f;
    unsigned u = v.u;
    return (unsigned short)((u + 0x7fffu + ((u >> 16) & 1u)) >> 16);
}

__device__ __forceinline__ float bits2f(unsigned u) {
    union { unsigned u; float f; } v; v.u = u;
    return v.f;
}

// ---------------- sort-by-target (counting sort) ----------------

__global__ void hist_kernel(const int* tgt, int* deg) {
    int e = blockIdx.x * blockDim.x + threadIdx.x;
    if (e < N_EDGES) atomicAdd(&deg[tgt[e]], 1);
}

__global__ __launch_bounds__(1024) void scan_kernel(const int* deg, int* starts,
                                                    int* cursor, float* dinv) {
    __shared__ int part[1024];
    int tid = threadIdx.x;
    const int PER = (N_NODES + 1023) / 1024;  // 10
    int base = tid * PER;
    int s = 0;
    for (int i = 0; i < PER; ++i) { int idx = base + i; if (idx < N_NODES) s += deg[idx]; }
    part[tid] = s; __syncthreads();
    for (int off = 1; off < 1024; off <<= 1) {
        int v = (tid >= off) ? part[tid - off] : 0;
        __syncthreads();
        part[tid] += v;
        __syncthreads();
    }
    int run = (tid > 0) ? part[tid - 1] : 0;
    for (int i = 0; i < PER; ++i) {
        int idx = base + i;
        if (idx < N_NODES) {
            int d = deg[idx];
            starts[idx] = run; cursor[idx] = run;
            dinv[idx] = 1.0f / (float)(d > 0 ? d : 1);
            run += d;
        }
    }
    if (tid == 1023) starts[N_NODES] = part[1023];
}

__global__ void scatter_kernel(const int* src, const int* tgt, const int* etype,
                               int* cursor, int* ssrc, int* stype) {
    int e = blockIdx.x * blockDim.x + threadIdx.x;
    if (e < N_EDGES) {
        int t = tgt[e];
        int pos = atomicAdd(&cursor[t], 1);
        ssrc[pos]  = src[e];
        stype[pos] = etype[e];
    }
}

// ---------------- bf16 operand prep ----------------
// B_ext[c][k] : k<KZ -> weight[b][kk][c] (k=b*200+kk); k in [KZ,KT) -> selfw[j][c]

__global__ void fill_bt_kernel(const float* weight, unsigned short* BW) {
    int idx = blockIdx.x * blockDim.x + threadIdx.x;
    if (idx >= NPAD * KZ) return;
    int n = idx / KZ, k = idx - n * KZ;
    float v = 0.f;
    if (n < DIM && k < N_BASES * DIM) {
        int b = k / DIM, kk = k - b * DIM;
        v = weight[(b * DIM + kk) * DIM + n];
    }
    BW[(size_t)n * KT + k] = f2bf(v);
}

__global__ void fill_wst_kernel(const float* sw, unsigned short* BW) {
    int idx = blockIdx.x * blockDim.x + threadIdx.x;
    if (idx >= NPAD * NPAD) return;
    int c = idx / NPAD, j = idx - c * NPAD;
    float v = (c < DIM && j < DIM) ? sw[j * DIM + c] : 0.f;
    BW[(size_t)c * KT + KZ + j] = f2bf(v);
}

// A_ext[n][KZ + j] = max(deg,1) * x[n][j]  (dinv in reduce epilogue undoes it)
__global__ void fill_xb_kernel(const float* x, const int* deg, unsigned short* ZX) {
    int idx = blockIdx.x * blockDim.x + threadIdx.x;
    if (idx >= N_NODES * NPAD) return;
    int n = idx / NPAD, j = idx - n * NPAD;
    float v = 0.f;
    if (j < DIM) {
        int d = deg[n]; if (d < 1) d = 1;
        v = (float)d * x[(size_t)n * DIM + j];
    }
    ZX[(size_t)n * KT + KZ + j] = f2bf(v);
}

// ---------------- per-target-node aggregation into Z ----------------
// Wave-per-node, barrier-free. Lane l (<50) owns cols 4l..4l+3; acc[30][4] in
// VGPRs. Coeff table staged once per block into LDS as bf16 (broadcast reads).

__global__ __launch_bounds__(256) void agg_kernel(const float* __restrict__ x,
                                                  const float* __restrict__ coeff,
                                                  const int* __restrict__ starts,
                                                  const int* __restrict__ ssrc,
                                                  const int* __restrict__ stype,
                                                  unsigned short* __restrict__ ZX) {
    __shared__ unsigned short c_lds[N_REL * N_BASES];  // 27600 B
    int tid = threadIdx.x;
    for (int i = tid; i < N_REL * N_BASES; i += 256)
        c_lds[i] = f2bf(coeff[i]);
    __syncthreads();

    int wave = tid >> 6;
    int lane = tid & 63;
    int n = blockIdx.x * 4 + wave;            // 2500*4 == 10000 exactly
    int cl = min(lane, 49);                   // clamp: lanes 50..63 duplicate

    float acc[N_BASES][4];
#pragma unroll
    for (int b = 0; b < N_BASES; ++b)
#pragma unroll
        for (int j = 0; j < 4; ++j) acc[b][j] = 0.f;

    int e0 = starts[n], e1 = starts[n + 1];
    const float4* x4 = (const float4*)x;      // 50 float4 per row

    float4 xvn = {0.f, 0.f, 0.f, 0.f};
    int tn = 0;
    if (e0 < e1) {
        int s0 = ssrc[e0];
        tn = stype[e0];
        xvn = x4[(size_t)s0 * 50 + cl];
    }

    for (int e = e0; e < e1; ++e) {
        float4 xv = xvn;
        int t = tn;
        const unsigned int* cw = (const unsigned int*)(c_lds + t * N_BASES);
        unsigned int w[N_BASES / 2];
#pragma unroll
        for (int i = 0; i < N_BASES / 2; ++i) w[i] = cw[i];  // broadcast ds_read

        if (e + 1 < e1) {                    // prefetch next edge
            int s1 = ssrc[e + 1];
            tn = stype[e + 1];
            xvn = x4[(size_t)s1 * 50 + cl];
        }

#pragma unroll
        for (int i = 0; i < N_BASES / 2; ++i) {
            float clo = bits2f(w[i] << 16);
            float chi = bits2f(w[i] & 0xffff0000u);
            acc[2 * i][0] += clo * xv.x; acc[2 * i][1] += clo * xv.y;
            acc[2 * i][2] += clo * xv.z; acc[2 * i][3] += clo * xv.w;
            acc[2 * i + 1][0] += chi * xv.x; acc[2 * i + 1][1] += chi * xv.y;
            acc[2 * i + 1][2] += chi * xv.z; acc[2 * i + 1][3] += chi * xv.w;
        }
    }

    if (lane < 50) {
        unsigned short* zr = ZX + (size_t)n * KT;
#pragma unroll
        for (int b = 0; b < N_BASES; ++b) {
            unsigned p0 = (unsigned)f2bf(acc[b][0]) | ((unsigned)f2bf(acc[b][1]) << 16);
            unsigned p1 = (unsigned)f2bf(acc[b][2]) | ((unsigned)f2bf(acc[b][3]) << 16);
            uint2 v; v.x = p0; v.y = p1;
            *(uint2*)(zr + b * DIM + lane * 4) = v;
        }
    }
}

// ---------------- GEMM: part[chunk] = A_ext @ B_ext^T over K-chunk ----------------
// Grid (313 tiles, 4 K-chunks), 4 waves/block: wave = (colgroup = w>>1, ksub = w&1).
// Each wave: 32 rows x 7 col-frags (112 cols), ~12 ksteps. LDS-reduce ksub pairs,
// write 32x208 fp32 partial. acc = 28 AGPR/wave.

__global__ __launch_bounds__(256) void gemm_kernel(const unsigned short* __restrict__ A,
                                                   const unsigned short* __restrict__ B,
                                                   float* __restrict__ part) {
    __shared__ float red[32 * 208];  // 26624 B
    int tid = threadIdx.x;
    int lane = tid & 63, wave = tid >> 6;
    int tile = blockIdx.x, chunk = blockIdx.y;
    int row0 = tile * 32;
    int cg = wave >> 1;               // col group: frags f0..f0+6
    int f0 = cg * 7;                  // 0..6 or 7..13 (frag 13 computed, discarded)

    int ks0 = chunk * 49;
    int ks1 = min(ks0 + 49, NSTEPS);
    int cnt = ks1 - ks0;
    int half = (cnt + 1) >> 1;
    int ks = ks0 + ((wave & 1) ? half : 0);
    int ke = (wave & 1) ? ks1 : ks0 + half;

    int ln = lane & 15, q = lane >> 4;
    int r0 = min(row0 + ln, N_NODES - 1);
    int r1 = min(row0 + 16 + ln, N_NODES - 1);
    const unsigned short* pa0 = A + (size_t)r0 * KT + q * 8;
    const unsigned short* pa1 = A + (size_t)r1 * KT + q * 8;
    const unsigned short* pb  = B + (size_t)(f0 * 16 + ln) * KT + q * 8;  // rows <= 223 < NPAD

    floatx4 acc0[7], acc1[7];
#pragma unroll
    for (int f = 0; f < 7; ++f) {
        acc0[f] = (floatx4){0.f, 0.f, 0.f, 0.f};
        acc1[f] = acc0[f];
    }

    for (int kk = ks; kk < ke; ++kk) {
        int k = kk * 32;
        short8 a0 = *(const short8*)(pa0 + k);
        short8 a1 = *(const short8*)(pa1 + k);
#pragma unroll
        for (int f = 0; f < 7; ++f) {
            short8 b = *(const short8*)(pb + (size_t)f * 16 * KT + k);
            acc0[f] = __builtin_amdgcn_mfma_f32_16x16x32_bf16(a0, b, acc0[f], 0, 0, 0);
            acc1[f] = __builtin_amdgcn_mfma_f32_16x16x32_bf16(a1, b, acc1[f], 0, 0, 0);
        }
    }

    // reduce the two K-subchunks: waves 0,2 write (disjoint cols), waves 1,3 add
    for (int w = 0; w < 2; ++w) {
        if ((wave & 1) == w) {
#pragma unroll
            for (int f = 0; f < 7; ++f) {
                int fg = f0 + f;
                if (fg < 13) {
                    int c = fg * 16 + ln;
#pragma unroll
                    for (int i = 0; i < 4; ++i) {
                        int ra = (q * 4 + i) * 208 + c;
                        int rb = (16 + q * 4 + i) * 208 + c;
                        if (w == 0) { red[ra] = acc0[f][i]; red[rb] = acc1[f][i]; }
                        else        { red[ra] += acc0[f][i]; red[rb] += acc1[f][i]; }
                    }
                }
            }
        }
        __syncthreads();
    }

    const float4* r4 = (const float4*)red;
    float4* p4 = (float4*)(part + ((size_t)chunk * PROWS + row0) * 208);
    for (int idx = tid; idx < 32 * 52; idx += 256) {
        int r = idx / 52;
        if (row0 + r < N_NODES) p4[idx] = r4[idx];
    }
}

// ---------------- reduce: out = dinv * sum(partials) + bias ----------------

__global__ __launch_bounds__(256) void reduce_kernel(const float* __restrict__ part,
                                                     const float* __restrict__ dinv,
                                                     const float* __restrict__ bias,
                                                     float* __restrict__ out) {
    int idx = blockIdx.x * blockDim.x + threadIdx.x;   // one float4 of output
    if (idx >= N_NODES * 50) return;
    int r = idx / 50, cq = idx - r * 50;
    float4 s = {0.f, 0.f, 0.f, 0.f};
#pragma unroll
    for (int c = 0; c < KSPLIT; ++c) {
        float4 v = *(const float4*)(part + ((size_t)c * PROWS + r) * 208 + cq * 4);
        s.x += v.x; s.y += v.y; s.z += v.z; s.w += v.w;
    }
    float dv = dinv[r];
    float4 b = *(const float4*)(bias + cq * 4);
    float4 o;
    o.x = s.x * dv + b.x; o.y = s.y * dv + b.y;
    o.z = s.z * dv + b.z; o.w = s.w * dv + b.w;
    *(float4*)(out + (size_t)r * DIM + cq * 4) = o;
}

// ---------------- launch ----------------

extern "C" void kernel_launch(void* const* d_in, const int* in_sizes, int n_in,
                              void* d_out, int out_size, void* d_ws, size_t ws_size,
                              hipStream_t stream) {
    const float* x      = (const float*)d_in[0];
    const float* weight = (const float*)d_in[1];
    const float* coeff  = (const float*)d_in[2];
    const float* selfw  = (const float*)d_in[3];
    const float* bias   = (const float*)d_in[4];
    const int*   eidx   = (const int*)d_in[5];
    const int*   etype  = (const int*)d_in[6];
    const int* src = eidx;
    const int* tgt = eidx + N_EDGES;
    float* out = (float*)d_out;

    char* ws = (char*)d_ws;
    size_t off = 0;
    auto carve = [&](size_t bytes) {
        char* p = ws + off;
        off += (bytes + 255) & ~(size_t)255;
        return p;
    };
    unsigned short* ZX  = (unsigned short*)carve((size_t)N_NODES * KT * 2);
    unsigned short* BW  = (unsigned short*)carve((size_t)NPAD * KT * 2);
    float* part   = (float*)carve((size_t)KSPLIT * PROWS * 208 * 4);
    int*   deg    = (int*)carve((size_t)N_NODES * 4);
    int*   starts = (int*)carve((size_t)(N_NODES + 1) * 4);
    int*   cursor = (int*)carve((size_t)N_NODES * 4);
    float* dinv   = (float*)carve((size_t)N_NODES * 4);
    int*   ssrc   = (int*)carve((size_t)N_EDGES * 4);
    int*   stype  = (int*)carve((size_t)N_EDGES * 4);

    hipMemsetAsync(deg, 0, (size_t)N_NODES * 4, stream);
    hist_kernel<<<(N_EDGES + 255) / 256, 256, 0, stream>>>(tgt, deg);
    scan_kernel<<<1, 1024, 0, stream>>>(deg, starts, cursor, dinv);
    scatter_kernel<<<(N_EDGES + 255) / 256, 256, 0, stream>>>(src, tgt, etype, cursor, ssrc, stype);

    fill_bt_kernel<<<(NPAD * KZ + 255) / 256, 256, 0, stream>>>(weight, BW);
    fill_wst_kernel<<<(NPAD * NPAD + 255) / 256, 256, 0, stream>>>(selfw, BW);
    fill_xb_kernel<<<(N_NODES * NPAD + 255) / 256, 256, 0, stream>>>(x, deg, ZX);

    agg_kernel<<<N_NODES / 4, 256, 0, stream>>>(x, coeff, starts, ssrc, stype, ZX);

    dim3 ggrid(NTILES, KSPLIT);
    gemm_kernel<<<ggrid, 256, 0, stream>>>(ZX, BW, part);

    reduce_kernel<<<(N_NODES * 50 + 255) / 256, 256, 0, stream>>>(part, dinv, bias, out);
}

// Round 5
// 330.691 us; speedup vs baseline: 2.0253x; 1.0999x over previous
//
#include <hip/hip_runtime.h>
#include <hip/hip_bf16.h>

#define N_NODES 10000
#define N_EDGES 320000
#define N_REL   460
#define N_BASES 30
#define DIM     200
#define KZ      6016   // 30*200=6000 padded to multiple of 32
#define KT      6240   // KZ + 224 (self-term columns appended)
#define NPAD    224    // 224 rows allocated for B (col dim padded)
#define NSTEPS  195    // KT/32
#define NTILES  313    // ceil(10000/32)
#define KSPLIT  4
#define PROWS   10016  // 313*32

using short8  = __attribute__((ext_vector_type(8))) short;
using floatx4 = __attribute__((ext_vector_type(4))) float;

__device__ __forceinline__ unsigned short f2bf(float f) {
    union { float f; unsigned u; } v; v.f = f;
    unsigned u = v.u;
    return (unsigned short)((u + 0x7fffu + ((u >> 16) & 1u)) >> 16);
}

__device__ __forceinline__ short8 pack8(const unsigned short* u) {
    union { unsigned short s[8]; short8 v; } p;
#pragma unroll
    for (int i = 0; i < 8; ++i) p.s[i] = u[i];
    return p.v;
}

// ---------------- sort-by-target (counting sort) ----------------

__global__ void hist_kernel(const int* tgt, int* deg) {
    int e = blockIdx.x * blockDim.x + threadIdx.x;
    if (e < N_EDGES) atomicAdd(&deg[tgt[e]], 1);
}

__global__ __launch_bounds__(1024) void scan_kernel(const int* deg, int* starts,
                                                    int* cursor, float* dinv) {
    __shared__ int part[1024];
    int tid = threadIdx.x;
    const int PER = (N_NODES + 1023) / 1024;  // 10
    int base = tid * PER;
    int s = 0;
    for (int i = 0; i < PER; ++i) { int idx = base + i; if (idx < N_NODES) s += deg[idx]; }
    part[tid] = s; __syncthreads();
    for (int off = 1; off < 1024; off <<= 1) {
        int v = (tid >= off) ? part[tid - off] : 0;
        __syncthreads();
        part[tid] += v;
        __syncthreads();
    }
    int run = (tid > 0) ? part[tid - 1] : 0;
    for (int i = 0; i < PER; ++i) {
        int idx = base + i;
        if (idx < N_NODES) {
            int d = deg[idx];
            starts[idx] = run; cursor[idx] = run;
            dinv[idx] = 1.0f / (float)(d > 0 ? d : 1);
            run += d;
        }
    }
    if (tid == 1023) starts[N_NODES] = part[1023];
}

__global__ void scatter_kernel(const int* src, const int* tgt, const int* etype,
                               int* cursor, int2* sedge) {
    int e = blockIdx.x * blockDim.x + threadIdx.x;
    if (e < N_EDGES) {
        int t = tgt[e];
        int pos = atomicAdd(&cursor[t], 1);
        sedge[pos] = make_int2(src[e], etype[e]);
    }
}

// ---------------- bf16 operand prep ----------------
// B_ext[c][k] : k<KZ -> weight[b][kk][c] (k=b*200+kk); k in [KZ,KT) -> selfw[j][c]

__global__ void fill_bt_kernel(const float* weight, unsigned short* BW) {
    int idx = blockIdx.x * blockDim.x + threadIdx.x;
    if (idx >= NPAD * KZ) return;
    int n = idx / KZ, k = idx - n * KZ;
    float v = 0.f;
    if (n < DIM && k < N_BASES * DIM) {
        int b = k / DIM, kk = k - b * DIM;
        v = weight[(b * DIM + kk) * DIM + n];
    }
    BW[(size_t)n * KT + k] = f2bf(v);
}

__global__ void fill_wst_kernel(const float* sw, unsigned short* BW) {
    int idx = blockIdx.x * blockDim.x + threadIdx.x;
    if (idx >= NPAD * NPAD) return;
    int c = idx / NPAD, j = idx - c * NPAD;
    float v = (c < DIM && j < DIM) ? sw[j * DIM + c] : 0.f;
    BW[(size_t)c * KT + KZ + j] = f2bf(v);
}

// A_ext[n][KZ + j] = max(deg,1) * x[n][j]  (dinv in reduce epilogue undoes it)
__global__ void fill_xb_kernel(const float* x, const int* deg, unsigned short* ZX) {
    int idx = blockIdx.x * blockDim.x + threadIdx.x;
    if (idx >= N_NODES * NPAD) return;
    int n = idx / NPAD, j = idx - n * NPAD;
    float v = 0.f;
    if (j < DIM) {
        int d = deg[n]; if (d < 1) d = 1;
        v = (float)d * x[(size_t)n * DIM + j];
    }
    ZX[(size_t)n * KT + KZ + j] = f2bf(v);
}

// bf16 copy of x for the agg gather (L2-resident, 4 MB)
__global__ void fill_xbf_kernel(const float* x, unsigned short* Xbf) {
    int idx = blockIdx.x * blockDim.x + threadIdx.x;
    if (idx >= N_NODES * DIM) return;
    Xbf[idx] = f2bf(x[idx]);
}

// Cpair[t][m] = bf16(coeff[t][m]) | bf16(coeff[t][m+16])<<16  (m=0..15; cols>=30 zero)
__global__ void fill_cpair_kernel(const float* coeff, unsigned int* Cpair) {
    int idx = blockIdx.x * blockDim.x + threadIdx.x;
    if (idx >= N_REL * 16) return;
    int t = idx >> 4, m = idx & 15;
    unsigned lo = f2bf(coeff[t * N_BASES + m]);
    unsigned hi = (m + 16 < N_BASES) ? f2bf(coeff[t * N_BASES + m + 16]) : 0u;
    Cpair[idx] = lo | (hi << 16);
}

// ---------------- per-target-node aggregation via MFMA ----------------
// Z[n] (30x200) = C_n^T (30 x deg) @ X_n (deg x 200), K padded to 32 with A=0.
// Wave-per-node, no LDS, no barriers. A-frag: Cpair dword loads (both m-tiles).
// B-frag: 8 ushort gathers per n-tile from bf16 Xbf.

__global__ __launch_bounds__(256) void agg_kernel(const unsigned short* __restrict__ Xbf,
                                                  const unsigned int* __restrict__ Cpair,
                                                  const int* __restrict__ starts,
                                                  const int2* __restrict__ sedge,
                                                  unsigned short* __restrict__ ZX) {
    int lane = threadIdx.x & 63;
    int wave = threadIdx.x >> 6;
    int n = blockIdx.x * 4 + wave;            // 2500*4 == 10000 exactly
    int ln = lane & 15, q = lane >> 4;

    floatx4 acc0[13], acc1[13];
#pragma unroll
    for (int f = 0; f < 13; ++f) {
        acc0[f] = (floatx4){0.f, 0.f, 0.f, 0.f};
        acc1[f] = acc0[f];
    }

    int e0 = starts[n], e1 = starts[n + 1];
    for (int kb = e0; kb < e1; kb += 32) {
        int eb = kb + 8 * q;
        unsigned short a0v[8], a1v[8];
        int srcs[8];
#pragma unroll
        for (int j = 0; j < 8; ++j) {
            int e = eb + j;
            int ec = (e < e1) ? e : (e1 - 1);
            int2 sd = sedge[ec];
            unsigned cp = (e < e1) ? Cpair[sd.y * 16 + ln] : 0u;
            a0v[j] = (unsigned short)(cp & 0xffffu);
            a1v[j] = (unsigned short)(cp >> 16);
            srcs[j] = sd.x;
        }
        short8 A0 = pack8(a0v), A1 = pack8(a1v);
#pragma unroll
        for (int f = 0; f < 13; ++f) {
            unsigned short bv[8];
#pragma unroll
            for (int j = 0; j < 8; ++j)
                bv[j] = Xbf[(size_t)srcs[j] * DIM + f * 16 + ln];
            short8 B = pack8(bv);
            acc0[f] = __builtin_amdgcn_mfma_f32_16x16x32_bf16(A0, B, acc0[f], 0, 0, 0);
            acc1[f] = __builtin_amdgcn_mfma_f32_16x16x32_bf16(A1, B, acc1[f], 0, 0, 0);
        }
    }

    // C-layout: col = ln (d-offset), row = q*4+i (base index within m-tile)
    unsigned short* zr = ZX + (size_t)n * KT;
#pragma unroll
    for (int f = 0; f < 13; ++f) {
        int d = f * 16 + ln;
        if (d < DIM) {
#pragma unroll
            for (int i = 0; i < 4; ++i) {
                int b0 = q * 4 + i;
                zr[b0 * DIM + d] = f2bf(acc0[f][i]);
                int b1 = 16 + q * 4 + i;
                if (b1 < N_BASES) zr[b1 * DIM + d] = f2bf(acc1[f][i]);
            }
        }
    }
}

// ---------------- GEMM: part[chunk] = A_ext @ B_ext^T over K-chunk ----------------
// Grid (313 tiles, 4 K-chunks), 4 waves/block: wave = (colgroup = w>>1, ksub = w&1).

__global__ __launch_bounds__(256) void gemm_kernel(const unsigned short* __restrict__ A,
                                                   const unsigned short* __restrict__ B,
                                                   float* __restrict__ part) {
    __shared__ float red[32 * 208];  // 26624 B
    int tid = threadIdx.x;
    int lane = tid & 63, wave = tid >> 6;
    int tile = blockIdx.x, chunk = blockIdx.y;
    int row0 = tile * 32;
    int cg = wave >> 1;
    int f0 = cg * 7;

    int ks0 = chunk * 49;
    int ks1 = min(ks0 + 49, NSTEPS);
    int cnt = ks1 - ks0;
    int half = (cnt + 1) >> 1;
    int ks = ks0 + ((wave & 1) ? half : 0);
    int ke = (wave & 1) ? ks1 : ks0 + half;

    int ln = lane & 15, q = lane >> 4;
    int r0 = min(row0 + ln, N_NODES - 1);
    int r1 = min(row0 + 16 + ln, N_NODES - 1);
    const unsigned short* pa0 = A + (size_t)r0 * KT + q * 8;
    const unsigned short* pa1 = A + (size_t)r1 * KT + q * 8;
    const unsigned short* pb  = B + (size_t)(f0 * 16 + ln) * KT + q * 8;

    floatx4 acc0[7], acc1[7];
#pragma unroll
    for (int f = 0; f < 7; ++f) {
        acc0[f] = (floatx4){0.f, 0.f, 0.f, 0.f};
        acc1[f] = acc0[f];
    }

    for (int kk = ks; kk < ke; ++kk) {
        int k = kk * 32;
        short8 a0 = *(const short8*)(pa0 + k);
        short8 a1 = *(const short8*)(pa1 + k);
#pragma unroll
        for (int f = 0; f < 7; ++f) {
            short8 b = *(const short8*)(pb + (size_t)f * 16 * KT + k);
            acc0[f] = __builtin_amdgcn_mfma_f32_16x16x32_bf16(a0, b, acc0[f], 0, 0, 0);
            acc1[f] = __builtin_amdgcn_mfma_f32_16x16x32_bf16(a1, b, acc1[f], 0, 0, 0);
        }
    }

    for (int w = 0; w < 2; ++w) {
        if ((wave & 1) == w) {
#pragma unroll
            for (int f = 0; f < 7; ++f) {
                int fg = f0 + f;
                if (fg < 13) {
                    int c = fg * 16 + ln;
#pragma unroll
                    for (int i = 0; i < 4; ++i) {
                        int ra = (q * 4 + i) * 208 + c;
                        int rb = (16 + q * 4 + i) * 208 + c;
                        if (w == 0) { red[ra] = acc0[f][i]; red[rb] = acc1[f][i]; }
                        else        { red[ra] += acc0[f][i]; red[rb] += acc1[f][i]; }
                    }
                }
            }
        }
        __syncthreads();
    }

    const float4* r4 = (const float4*)red;
    float4* p4 = (float4*)(part + ((size_t)chunk * PROWS + row0) * 208);
    for (int idx = tid; idx < 32 * 52; idx += 256) {
        int r = idx / 52;
        if (row0 + r < N_NODES) p4[idx] = r4[idx];
    }
}

// ---------------- reduce: out = dinv * sum(partials) + bias ----------------

__global__ __launch_bounds__(256) void reduce_kernel(const float* __restrict__ part,
                                                     const float* __restrict__ dinv,
                                                     const float* __restrict__ bias,
                                                     float* __restrict__ out) {
    int idx = blockIdx.x * blockDim.x + threadIdx.x;
    if (idx >= N_NODES * 50) return;
    int r = idx / 50, cq = idx - r * 50;
    float4 s = {0.f, 0.f, 0.f, 0.f};
#pragma unroll
    for (int c = 0; c < KSPLIT; ++c) {
        float4 v = *(const float4*)(part + ((size_t)c * PROWS + r) * 208 + cq * 4);
        s.x += v.x; s.y += v.y; s.z += v.z; s.w += v.w;
    }
    float dv = dinv[r];
    float4 b = *(const float4*)(bias + cq * 4);
    float4 o;
    o.x = s.x * dv + b.x; o.y = s.y * dv + b.y;
    o.z = s.z * dv + b.z; o.w = s.w * dv + b.w;
    *(float4*)(out + (size_t)r * DIM + cq * 4) = o;
}

// ---------------- launch ----------------

extern "C" void kernel_launch(void* const* d_in, const int* in_sizes, int n_in,
                              void* d_out, int out_size, void* d_ws, size_t ws_size,
                              hipStream_t stream) {
    const float* x      = (const float*)d_in[0];
    const float* weight = (const float*)d_in[1];
    const float* coeff  = (const float*)d_in[2];
    const float* selfw  = (const float*)d_in[3];
    const float* bias   = (const float*)d_in[4];
    const int*   eidx   = (const int*)d_in[5];
    const int*   etype  = (const int*)d_in[6];
    const int* src = eidx;
    const int* tgt = eidx + N_EDGES;
    float* out = (float*)d_out;

    char* ws = (char*)d_ws;
    size_t off = 0;
    auto carve = [&](size_t bytes) {
        char* p = ws + off;
        off += (bytes + 255) & ~(size_t)255;
        return p;
    };
    unsigned short* ZX   = (unsigned short*)carve((size_t)N_NODES * KT * 2);
    unsigned short* BW   = (unsigned short*)carve((size_t)NPAD * KT * 2);
    float* part   = (float*)carve((size_t)KSPLIT * PROWS * 208 * 4);
    unsigned short* Xbf  = (unsigned short*)carve((size_t)(N_NODES * DIM + 64) * 2);
    unsigned int*  Cpair = (unsigned int*)carve((size_t)N_REL * 16 * 4);
    int*   deg    = (int*)carve((size_t)N_NODES * 4);
    int*   starts = (int*)carve((size_t)(N_NODES + 1) * 4);
    int*   cursor = (int*)carve((size_t)N_NODES * 4);
    float* dinv   = (float*)carve((size_t)N_NODES * 4);
    int2*  sedge  = (int2*)carve((size_t)N_EDGES * 8);

    hipMemsetAsync(deg, 0, (size_t)N_NODES * 4, stream);
    hist_kernel<<<(N_EDGES + 255) / 256, 256, 0, stream>>>(tgt, deg);
    scan_kernel<<<1, 1024, 0, stream>>>(deg, starts, cursor, dinv);
    scatter_kernel<<<(N_EDGES + 255) / 256, 256, 0, stream>>>(src, tgt, etype, cursor, sedge);

    fill_bt_kernel<<<(NPAD * KZ + 255) / 256, 256, 0, stream>>>(weight, BW);
    fill_wst_kernel<<<(NPAD * NPAD + 255) / 256, 256, 0, stream>>>(selfw, BW);
    fill_xb_kernel<<<(N_NODES * NPAD + 255) / 256, 256, 0, stream>>>(x, deg, ZX);
    fill_xbf_kernel<<<(N_NODES * DIM + 255) / 256, 256, 0, stream>>>(x, Xbf);
    fill_cpair_kernel<<<(N_REL * 16 + 255) / 256, 256, 0, stream>>>(coeff, Cpair);

    agg_kernel<<<N_NODES / 4, 256, 0, stream>>>(Xbf, Cpair, starts, sedge, ZX);

    dim3 ggrid(NTILES, KSPLIT);
    gemm_kernel<<<ggrid, 256, 0, stream>>>(ZX, BW, part);

    reduce_kernel<<<(N_NODES * 50 + 255) / 256, 256, 0, stream>>>(part, dinv, bias, out);
}